// Round 16
// baseline (1707.366 us; speedup 1.0000x reference)
//
#include <hip/hip_runtime.h>

#define VOCAB 32000
#define EMB 32
#define HID 16
#define SEQ 128
#define BATCH 32
#define NROW (SEQ * BATCH)  // 4096 rows

// ATTRIBUTION ROUND: every kernel REP-inflated past the ~305us harness fills
// so all four surface in the top-5 with full counter rows. Idempotent reps.
#define REP_EMB  128
#define REP_RNN  24
#define REP_SUM  14
#define REP_WRI  3

typedef float f32x2 __attribute__((ext_vector_type(2)));
typedef float f32x4 __attribute__((ext_vector_type(4)));

// ---------------------------------------------------------------------------
// K0: A = X@Wx (parallel, R14). REP x128.
// ---------------------------------------------------------------------------
__global__ __launch_bounds__(512) void embed_x128(
    const int* __restrict__ idx, const float* __restrict__ lookup,
    const float* __restrict__ Wx, float* __restrict__ A)
{
    __shared__ float sWx[EMB][HID];
    const int tid = threadIdx.x;
    ((float*)sWx)[tid] = Wx[tid];  // 512 == EMB*HID
    __syncthreads();

    const int g = blockIdx.x * 512 + tid;
    const int row = g >> 4, j = g & 15;

    #pragma unroll 1
    for (int rep = 0; rep < REP_EMB; ++rep) {
        const float* xr = lookup + (size_t)idx[row] * EMB;
        float a0 = 0.f, a1 = 0.f;
        #pragma unroll
        for (int e = 0; e < EMB; e += 2) {
            a0 += xr[e] * sWx[e][j];
            a1 += xr[e + 1] * sWx[e + 1][j];
        }
        A[g] = a0 + a1;
        asm volatile("" ::: "memory");
    }
}

// ---------------------------------------------------------------------------
// K1: serial recurrence (R14). REP x24 (full restart each rep: idempotent).
// ---------------------------------------------------------------------------
__global__ __launch_bounds__(512) void rnn_x24(
    const float* __restrict__ A, const float* __restrict__ Wh,
    float* __restrict__ Hout)
{
    __shared__ __align__(16) float sH[BATCH][HID];

    const int tid = threadIdx.x;
    const int b = tid >> 4, j = tid & 15;

    float wh[HID];
    #pragma unroll
    for (int k = 0; k < HID; ++k) wh[k] = Wh[k * HID + j];  // column j

    #pragma unroll 1
    for (int rep = 0; rep < REP_RNN; ++rep) {
        sH[b][j] = 1.0f;  // torch inits H to ones (reset each rep)
        __syncthreads();

        float a0r = A[0 * 512 + tid];
        float a1r = A[1 * 512 + tid];
        float a2r = A[2 * 512 + tid];
        float a3r = A[3 * 512 + tid];

#define RNN_STEP(AR, T)                                                     \
        {                                                                   \
            float acc = AR;                                                 \
            if ((T) + 4 < SEQ) AR = A[((T) + 4) * 512 + tid];               \
            const f32x4* sH4 = (const f32x4*)&sH[b][0];                     \
            f32x4 h0 = sH4[0], h1 = sH4[1], h2v = sH4[2], h3v = sH4[3];     \
            acc += h0.x * wh[0] + h0.y * wh[1] + h0.z * wh[2]               \
                 + h0.w * wh[3];                                            \
            acc += h1.x * wh[4] + h1.y * wh[5] + h1.z * wh[6]               \
                 + h1.w * wh[7];                                            \
            acc += h2v.x * wh[8] + h2v.y * wh[9] + h2v.z * wh[10]           \
                 + h2v.w * wh[11];                                          \
            acc += h3v.x * wh[12] + h3v.y * wh[13] + h3v.z * wh[14]         \
                 + h3v.w * wh[15];                                          \
            float e2 = __expf(2.f * acc);                                   \
            float h = 1.f - 2.f / (e2 + 1.f);                               \
            sH[b][j] = h;                                                   \
            Hout[(T) * 512 + tid] = h;                                      \
        }

        for (int t = 0; t < SEQ; t += 4) {
            RNN_STEP(a0r, t + 0)
            RNN_STEP(a1r, t + 1)
            RNN_STEP(a2r, t + 2)
            RNN_STEP(a3r, t + 3)
        }
#undef RNN_STEP
        asm volatile("" ::: "memory");
        __syncthreads();  // all reads done before next rep's sH reset
    }
}

// ---------------------------------------------------------------------------
// K2: sum-of-exp, lane=row (R14, est ~25us). REP x14.
// ---------------------------------------------------------------------------
#define CSL 500  // cols per wave slice

__global__ __launch_bounds__(512, 4) void sum_x14(
    const float* __restrict__ H, const float* __restrict__ Wo,
    float* __restrict__ P)
{
    __shared__ float part[8][64];

    const int tid = threadIdx.x;
    const int lane = tid & 63;
    const int wave = tid >> 6;
    const int rgrp = blockIdx.x >> 3;
    const int cchunk = blockIdx.x & 7;
    const int row0 = rgrp * 64;
    const int c0 = __builtin_amdgcn_readfirstlane(cchunk * 4000 + wave * CSL);

    f32x2 hp[HID];
    {
        const f32x4* h4 = (const f32x4*)(H + (size_t)(row0 + lane) * HID);
        #pragma unroll
        for (int q = 0; q < 4; ++q) {
            f32x4 hv = h4[q];
            hp[4 * q + 0] = f32x2{hv.x, hv.x};
            hp[4 * q + 1] = f32x2{hv.y, hv.y};
            hp[4 * q + 2] = f32x2{hv.z, hv.z};
            hp[4 * q + 3] = f32x2{hv.w, hv.w};
        }
    }

    #pragma unroll 1
    for (int rep = 0; rep < REP_SUM; ++rep) {
        const float* wbase = Wo + c0;
        float acc0 = 0.f, acc1 = 0.f, acc2 = 0.f, acc3 = 0.f;
        for (int v = 0; v < CSL; v += 4) {
            f32x2 a01 = {0.f, 0.f}, a23 = {0.f, 0.f};
            #pragma unroll
            for (int k = 0; k < HID; ++k) {
                f32x4 w4 = *(const f32x4*)(wbase + (size_t)k * VOCAB + v);
                asm("v_pk_fma_f32 %0, %1, %2, %0"
                    : "+v"(a01) : "v"(hp[k]), "s"(w4.xy));
                asm("v_pk_fma_f32 %0, %1, %2, %0"
                    : "+v"(a23) : "v"(hp[k]), "s"(w4.zw));
            }
            acc0 += __expf(a01.x); acc1 += __expf(a01.y);
            acc2 += __expf(a23.x); acc3 += __expf(a23.y);
        }

        part[wave][lane] = (acc0 + acc1) + (acc2 + acc3);
        __syncthreads();
        if (wave == 0) {
            float tot = 0.f;
            #pragma unroll
            for (int w = 0; w < 8; ++w) tot += part[w][lane];
            P[(size_t)cchunk * NROW + row0 + lane] = tot;
        }
        asm volatile("" ::: "memory");
        __syncthreads();
    }
}

// ---------------------------------------------------------------------------
// K3: output pass — R14 per-row structure, NT stores (R15: plain no better,
// blocking no better). REP x3.
// ---------------------------------------------------------------------------
#define RV 64     // rows per block
#define VSK 2048  // vocab cols per block slice

__global__ __launch_bounds__(512, 4) void write_x3(
    const float* __restrict__ H, const float* __restrict__ Wo,
    const float* __restrict__ P, float* __restrict__ out)
{
    __shared__ __align__(16) float sH[RV * HID];  // 4 KB
    __shared__ __align__(16) float sLogS[RV];

    const int tid = threadIdx.x;
    const int vtile = blockIdx.x & 15;
    const int row0 = (blockIdx.x >> 4) * RV;

    if (tid < RV * HID / 4)
        *(float4*)(sH + 4 * tid) = *(const float4*)(H + row0 * HID + 4 * tid);
    if (tid < RV) {  // fused logS: 8 partials per row
        float tot = 0.f;
        #pragma unroll
        for (int p = 0; p < 8; ++p) tot += P[(size_t)p * NROW + row0 + tid];
        sLogS[tid] = __logf(tot);
    }
    __syncthreads();

    const int v = vtile * VSK + 4 * tid;
    if (v >= VOCAB) return;  // tail; no barriers below

    const f32x4* sH4 = (const f32x4*)sH;
    const f32x4* sLS4 = (const f32x4*)sLogS;

    #pragma unroll 1
    for (int rep = 0; rep < REP_WRI; ++rep) {
        f32x2 wlo[HID], whi[HID];
        #pragma unroll
        for (int k = 0; k < HID; ++k) {
            f32x4 w4 = *(const f32x4*)(Wo + (size_t)k * VOCAB + v);
            wlo[k] = w4.xy; whi[k] = w4.zw;
        }
        float* orow = out + (size_t)row0 * VOCAB + v;
        for (int r4 = 0; r4 < RV; r4 += 4) {
            f32x4 ls4 = sLS4[r4 >> 2];
            #pragma unroll
            for (int rr = 0; rr < 4; ++rr) {
                const int r = r4 + rr;
                f32x2 l01 = {0.f, 0.f}, l23 = {0.f, 0.f};
                #pragma unroll
                for (int q = 0; q < 4; ++q) {
                    f32x4 hv = sH4[r * 4 + q];
                    l01 += hv.x * wlo[4*q+0]; l23 += hv.x * whi[4*q+0];
                    l01 += hv.y * wlo[4*q+1]; l23 += hv.y * whi[4*q+1];
                    l01 += hv.z * wlo[4*q+2]; l23 += hv.z * whi[4*q+2];
                    l01 += hv.w * wlo[4*q+3]; l23 += hv.w * whi[4*q+3];
                }
                const float ls = (rr == 0) ? ls4.x : (rr == 1) ? ls4.y
                               : (rr == 2) ? ls4.z : ls4.w;
                f32x4 o;
                o.xy = l01 - ls;
                o.zw = l23 - ls;
                __builtin_nontemporal_store(o, (f32x4*)orow);
                orow += VOCAB;
            }
        }
        asm volatile("" ::: "memory");
    }
}

extern "C" void kernel_launch(void* const* d_in, const int* in_sizes, int n_in,
                              void* d_out, int out_size, void* d_ws, size_t ws_size,
                              hipStream_t stream) {
    const int*   idx    = (const int*)d_in[0];    // [SEQ, BATCH] int32
    const float* lookup = (const float*)d_in[1];  // [VOCAB, EMB]
    const float* Wx     = (const float*)d_in[2];  // [EMB, HID]
    const float* Wh     = (const float*)d_in[3];  // [HID, HID]
    const float* Wo     = (const float*)d_in[4];  // [HID, VOCAB]
    float* out = (float*)d_out;                   // [SEQ, BATCH, VOCAB]

    // ws layout: H (256 KB) | A = X@Wx (256 KB) | P partials 8x4096 (128 KB)
    float* Hbuf = (float*)d_ws;
    float* A    = Hbuf + NROW * HID;
    float* P    = A + NROW * HID;

    embed_x128<<<128, 512, 0, stream>>>(idx, lookup, Wx, A);
    rnn_x24<<<1, 512, 0, stream>>>(A, Wh, Hbuf);
    sum_x14<<<512, 512, 0, stream>>>(Hbuf, Wo, P);
    write_x3<<<16 * (NROW / RV), 512, 0, stream>>>(Hbuf, Wo, P, out);
}

// Round 17
// 217.009 us; speedup vs baseline: 7.8677x; 7.8677x over previous
//
#include <hip/hip_runtime.h>

#define VOCAB 32000
#define EMB 32
#define HID 16
#define SEQ 128
#define BATCH 32
#define NROW (SEQ * BATCH)  // 4096 rows

typedef float f32x2 __attribute__((ext_vector_type(2)));
typedef float f32x4 __attribute__((ext_vector_type(4)));

// ---------------------------------------------------------------------------
// K0: A = X@Wx (parallel, R14).
// ---------------------------------------------------------------------------
__global__ __launch_bounds__(512) void embed_xw(
    const int* __restrict__ idx, const float* __restrict__ lookup,
    const float* __restrict__ Wx, float* __restrict__ A)
{
    __shared__ float sWx[EMB][HID];
    const int tid = threadIdx.x;
    ((float*)sWx)[tid] = Wx[tid];  // 512 == EMB*HID
    __syncthreads();

    const int g = blockIdx.x * 512 + tid;
    const int row = g >> 4, j = g & 15;
    const float* xr = lookup + (size_t)idx[row] * EMB;
    float a0 = 0.f, a1 = 0.f;
    #pragma unroll
    for (int e = 0; e < EMB; e += 2) {
        a0 += xr[e] * sWx[e][j];
        a1 += xr[e + 1] * sWx[e + 1][j];
    }
    A[g] = a0 + a1;
}

// ---------------------------------------------------------------------------
// K1: serial recurrence (R14). One block, 512 thr = 32b x 16j; no per-step
// barrier (16-lane-group locality, rounds 1-16).
// ---------------------------------------------------------------------------
__global__ __launch_bounds__(512) void rnn_recur(
    const float* __restrict__ A, const float* __restrict__ Wh,
    float* __restrict__ Hout)
{
    __shared__ __align__(16) float sH[BATCH][HID];

    const int tid = threadIdx.x;
    const int b = tid >> 4, j = tid & 15;

    float wh[HID];
    #pragma unroll
    for (int k = 0; k < HID; ++k) wh[k] = Wh[k * HID + j];  // column j

    sH[b][j] = 1.0f;  // torch inits H to ones
    __syncthreads();

    float a0r = A[0 * 512 + tid];
    float a1r = A[1 * 512 + tid];
    float a2r = A[2 * 512 + tid];
    float a3r = A[3 * 512 + tid];

#define RNN_STEP(AR, T)                                                     \
    {                                                                       \
        float acc = AR;                                                     \
        if ((T) + 4 < SEQ) AR = A[((T) + 4) * 512 + tid];                   \
        const f32x4* sH4 = (const f32x4*)&sH[b][0];                         \
        f32x4 h0 = sH4[0], h1 = sH4[1], h2v = sH4[2], h3v = sH4[3];         \
        acc += h0.x * wh[0] + h0.y * wh[1] + h0.z * wh[2] + h0.w * wh[3];   \
        acc += h1.x * wh[4] + h1.y * wh[5] + h1.z * wh[6] + h1.w * wh[7];   \
        acc += h2v.x * wh[8] + h2v.y * wh[9] + h2v.z * wh[10]               \
             + h2v.w * wh[11];                                              \
        acc += h3v.x * wh[12] + h3v.y * wh[13] + h3v.z * wh[14]             \
             + h3v.w * wh[15];                                              \
        float e2 = __expf(2.f * acc);   /* tanh = 1 - 2/(e^{2a}+1) */       \
        float h = 1.f - 2.f / (e2 + 1.f);                                   \
        sH[b][j] = h;                                                       \
        Hout[(T) * 512 + tid] = h;                                          \
    }

    for (int t = 0; t < SEQ; t += 4) {
        RNN_STEP(a0r, t + 0)
        RNN_STEP(a1r, t + 1)
        RNN_STEP(a2r, t + 2)
        RNN_STEP(a3r, t + 3)
    }
#undef RNN_STEP
}

// ---------------------------------------------------------------------------
// K2 (v3): sum-of-exp, lane=row (R14/R16: 67us, VALUBusy 67%, Occ 38%,
// SGPR=96 -> SMEM path confirmed; 33% stall = un-hidden s_load latency at
// 2 blocks/CU). This round: (1) 256-thr blocks x grid 1024 -> 8 blocks/CU,
// 32 waves/CU to hide SMEM latency; (2) v-loop unroll 2 for SMEM overlap;
// (3) H pre-scaled by log2e -> raw v_exp_f32 (exp2), saves 4 muls/iter.
// ---------------------------------------------------------------------------
#define CSL 500   // cols per wave slice; 16 chunks x 4 waves x 500 = 32000

__global__ __launch_bounds__(256, 8) void sum_exp_partial(
    const float* __restrict__ H, const float* __restrict__ Wo,
    float* __restrict__ P)
{
    __shared__ float part[4][64];

    const int tid = threadIdx.x;
    const int lane = tid & 63;
    const int wave = tid >> 6;                    // 0..3
    const int rgrp = blockIdx.x >> 4;             // 0..63
    const int cchunk = blockIdx.x & 15;           // 0..15
    const int row0 = rgrp * 64;
    const int c0 = __builtin_amdgcn_readfirstlane(cchunk * 2000 + wave * CSL);

    const float LOG2E = 1.4426950408889634f;
    f32x2 hp[HID];  // per-lane H row, pre-scaled by log2e
    {
        const f32x4* h4 = (const f32x4*)(H + (size_t)(row0 + lane) * HID);
        #pragma unroll
        for (int q = 0; q < 4; ++q) {
            f32x4 hv = h4[q];
            float x0 = hv.x * LOG2E, x1 = hv.y * LOG2E;
            float x2 = hv.z * LOG2E, x3 = hv.w * LOG2E;
            hp[4 * q + 0] = f32x2{x0, x0};
            hp[4 * q + 1] = f32x2{x1, x1};
            hp[4 * q + 2] = f32x2{x2, x2};
            hp[4 * q + 3] = f32x2{x3, x3};
        }
    }

    const float* wbase = Wo + c0;
    float acc0 = 0.f, acc1 = 0.f, acc2 = 0.f, acc3 = 0.f;
    #pragma unroll 2
    for (int v = 0; v < CSL; v += 4) {
        f32x2 a01 = {0.f, 0.f}, a23 = {0.f, 0.f};
        #pragma unroll
        for (int k = 0; k < HID; ++k) {
            f32x4 w4 = *(const f32x4*)(wbase + (size_t)k * VOCAB + v);
            asm("v_pk_fma_f32 %0, %1, %2, %0"
                : "+v"(a01) : "v"(hp[k]), "s"(w4.xy));
            asm("v_pk_fma_f32 %0, %1, %2, %0"
                : "+v"(a23) : "v"(hp[k]), "s"(w4.zw));
        }
        // accumulators hold l*log2e -> native exp2
        acc0 += __builtin_amdgcn_exp2f(a01.x);
        acc1 += __builtin_amdgcn_exp2f(a01.y);
        acc2 += __builtin_amdgcn_exp2f(a23.x);
        acc3 += __builtin_amdgcn_exp2f(a23.y);
    }

    part[wave][lane] = (acc0 + acc1) + (acc2 + acc3);
    __syncthreads();
    if (wave == 0) {
        float tot = part[0][lane] + part[1][lane]
                  + part[2][lane] + part[3][lane];
        P[(size_t)cchunk * NROW + row0 + lane] = tot;  // written exactly once
    }
}

// ---------------------------------------------------------------------------
// K3: output pass — R14 structure (107us = NT plateau; R15: plain stores and
// row-blocking both no better). logS fused from 16 partials. NT stores.
// ---------------------------------------------------------------------------
#define RV 64     // rows per block
#define VSK 2048  // vocab cols per block slice

__global__ __launch_bounds__(512, 4) void write_logits(
    const float* __restrict__ H, const float* __restrict__ Wo,
    const float* __restrict__ P, float* __restrict__ out)
{
    __shared__ __align__(16) float sH[RV * HID];  // 4 KB
    __shared__ __align__(16) float sLogS[RV];

    const int tid = threadIdx.x;
    const int vtile = blockIdx.x & 15;
    const int row0 = (blockIdx.x >> 4) * RV;

    if (tid < RV * HID / 4)
        *(float4*)(sH + 4 * tid) = *(const float4*)(H + row0 * HID + 4 * tid);
    if (tid < RV) {  // fused logS: 16 partials per row
        float tot = 0.f;
        #pragma unroll
        for (int p = 0; p < 16; ++p) tot += P[(size_t)p * NROW + row0 + tid];
        sLogS[tid] = __logf(tot);
    }
    __syncthreads();

    const int v = vtile * VSK + 4 * tid;
    if (v >= VOCAB) return;  // tile-15 tail; no barriers below

    f32x2 wlo[HID], whi[HID];
    #pragma unroll
    for (int k = 0; k < HID; ++k) {
        f32x4 w4 = *(const f32x4*)(Wo + (size_t)k * VOCAB + v);
        wlo[k] = w4.xy; whi[k] = w4.zw;
    }
    const f32x4* sH4 = (const f32x4*)sH;
    const f32x4* sLS4 = (const f32x4*)sLogS;

    float* orow = out + (size_t)row0 * VOCAB + v;
    for (int r4 = 0; r4 < RV; r4 += 4) {
        f32x4 ls4 = sLS4[r4 >> 2];
        #pragma unroll
        for (int rr = 0; rr < 4; ++rr) {
            const int r = r4 + rr;
            f32x2 l01 = {0.f, 0.f}, l23 = {0.f, 0.f};
            #pragma unroll
            for (int q = 0; q < 4; ++q) {
                f32x4 hv = sH4[r * 4 + q];  // uniform addr b128 broadcast
                l01 += hv.x * wlo[4*q+0]; l23 += hv.x * whi[4*q+0];
                l01 += hv.y * wlo[4*q+1]; l23 += hv.y * whi[4*q+1];
                l01 += hv.z * wlo[4*q+2]; l23 += hv.z * whi[4*q+2];
                l01 += hv.w * wlo[4*q+3]; l23 += hv.w * whi[4*q+3];
            }
            const float ls = (rr == 0) ? ls4.x : (rr == 1) ? ls4.y
                           : (rr == 2) ? ls4.z : ls4.w;
            f32x4 o;
            o.xy = l01 - ls;
            o.zw = l23 - ls;
            __builtin_nontemporal_store(o, (f32x4*)orow);
            orow += VOCAB;
        }
    }
}

extern "C" void kernel_launch(void* const* d_in, const int* in_sizes, int n_in,
                              void* d_out, int out_size, void* d_ws, size_t ws_size,
                              hipStream_t stream) {
    const int*   idx    = (const int*)d_in[0];    // [SEQ, BATCH] int32
    const float* lookup = (const float*)d_in[1];  // [VOCAB, EMB]
    const float* Wx     = (const float*)d_in[2];  // [EMB, HID]
    const float* Wh     = (const float*)d_in[3];  // [HID, HID]
    const float* Wo     = (const float*)d_in[4];  // [HID, VOCAB]
    float* out = (float*)d_out;                   // [SEQ, BATCH, VOCAB]

    // ws layout: H (256 KB) | A = X@Wx (256 KB, dead after rnn) reused as
    // P partials 16x4096 (256 KB) — kernels are stream-serialized.
    float* Hbuf = (float*)d_ws;
    float* A    = Hbuf + NROW * HID;
    float* P    = A;  // alias: A consumed by rnn_recur before sum writes P

    embed_xw<<<128, 512, 0, stream>>>(idx, lookup, Wx, A);
    rnn_recur<<<1, 512, 0, stream>>>(A, Wh, Hbuf);
    sum_exp_partial<<<64 * 16, 256, 0, stream>>>(Hbuf, Wo, P);
    write_logits<<<16 * (NROW / RV), 512, 0, stream>>>(Hbuf, Wo, P, out);
}

// Round 18
// 216.795 us; speedup vs baseline: 7.8755x; 1.0010x over previous
//
#include <hip/hip_runtime.h>

#define VOCAB 32000
#define EMB 32
#define HID 16
#define SEQ 128
#define BATCH 32
#define NROW (SEQ * BATCH)  // 4096 rows

typedef float f32x2  __attribute__((ext_vector_type(2)));
typedef float f32x4  __attribute__((ext_vector_type(4)));
typedef float f32x16 __attribute__((ext_vector_type(16)));

// ---------------------------------------------------------------------------
// K0: A = X@Wx (parallel, R14).
// ---------------------------------------------------------------------------
__global__ __launch_bounds__(512) void embed_xw(
    const int* __restrict__ idx, const float* __restrict__ lookup,
    const float* __restrict__ Wx, float* __restrict__ A)
{
    __shared__ float sWx[EMB][HID];
    const int tid = threadIdx.x;
    ((float*)sWx)[tid] = Wx[tid];  // 512 == EMB*HID
    __syncthreads();

    const int g = blockIdx.x * 512 + tid;
    const int row = g >> 4, j = g & 15;
    const float* xr = lookup + (size_t)idx[row] * EMB;
    float a0 = 0.f, a1 = 0.f;
    #pragma unroll
    for (int e = 0; e < EMB; e += 2) {
        a0 += xr[e] * sWx[e][j];
        a1 += xr[e + 1] * sWx[e + 1][j];
    }
    A[g] = a0 + a1;
}

// ---------------------------------------------------------------------------
// K1: serial recurrence (R14); no per-step barrier (16-lane-group locality).
// ---------------------------------------------------------------------------
__global__ __launch_bounds__(512) void rnn_recur(
    const float* __restrict__ A, const float* __restrict__ Wh,
    float* __restrict__ Hout)
{
    __shared__ __align__(16) float sH[BATCH][HID];

    const int tid = threadIdx.x;
    const int b = tid >> 4, j = tid & 15;

    float wh[HID];
    #pragma unroll
    for (int k = 0; k < HID; ++k) wh[k] = Wh[k * HID + j];  // column j

    sH[b][j] = 1.0f;  // torch inits H to ones
    __syncthreads();

    float a0r = A[0 * 512 + tid];
    float a1r = A[1 * 512 + tid];
    float a2r = A[2 * 512 + tid];
    float a3r = A[3 * 512 + tid];

#define RNN_STEP(AR, T)                                                     \
    {                                                                       \
        float acc = AR;                                                     \
        if ((T) + 4 < SEQ) AR = A[((T) + 4) * 512 + tid];                   \
        const f32x4* sH4 = (const f32x4*)&sH[b][0];                         \
        f32x4 h0 = sH4[0], h1 = sH4[1], h2v = sH4[2], h3v = sH4[3];         \
        acc += h0.x * wh[0] + h0.y * wh[1] + h0.z * wh[2] + h0.w * wh[3];   \
        acc += h1.x * wh[4] + h1.y * wh[5] + h1.z * wh[6] + h1.w * wh[7];   \
        acc += h2v.x * wh[8] + h2v.y * wh[9] + h2v.z * wh[10]               \
             + h2v.w * wh[11];                                              \
        acc += h3v.x * wh[12] + h3v.y * wh[13] + h3v.z * wh[14]             \
             + h3v.w * wh[15];                                              \
        float e2 = __expf(2.f * acc);   /* tanh = 1 - 2/(e^{2a}+1) */       \
        float h = 1.f - 2.f / (e2 + 1.f);                                   \
        sH[b][j] = h;                                                       \
        Hout[(T) * 512 + tid] = h;                                          \
    }

    for (int t = 0; t < SEQ; t += 4) {
        RNN_STEP(a0r, t + 0)
        RNN_STEP(a1r, t + 1)
        RNN_STEP(a2r, t + 2)
        RNN_STEP(a3r, t + 3)
    }
#undef RNN_STEP
}

// ---------------------------------------------------------------------------
// K2 (v5): sum-of-exp, lane=row. R17 lesson: stall is SMEM-PIPE INSTRUCTION
// COUNT (per-CU scalar pipe; occupancy doesn't help). Fix: 16-col iterations
// with f32x16 uniform loads (s_load_dwordx16, 64 B/instr) -> 4x fewer SMEM
// instrs at identical pk_fma work. 31 x 16-col iters + one 4-col tail = 500.
// ---------------------------------------------------------------------------
#define CSL 500   // cols per wave slice; 16 chunks x 4 waves x 500 = 32000

__global__ __launch_bounds__(256, 8) void sum_exp_partial(
    const float* __restrict__ H, const float* __restrict__ Wo,
    float* __restrict__ P)
{
    __shared__ float part[4][64];

    const int tid = threadIdx.x;
    const int lane = tid & 63;
    const int wave = tid >> 6;                    // 0..3
    const int rgrp = blockIdx.x >> 4;             // 0..63
    const int cchunk = blockIdx.x & 15;           // 0..15
    const int row0 = rgrp * 64;
    const int c0 = __builtin_amdgcn_readfirstlane(cchunk * 2000 + wave * CSL);

    const float LOG2E = 1.4426950408889634f;
    f32x2 hp[HID];  // per-lane H row, pre-scaled by log2e
    {
        const f32x4* h4 = (const f32x4*)(H + (size_t)(row0 + lane) * HID);
        #pragma unroll
        for (int q = 0; q < 4; ++q) {
            f32x4 hv = h4[q];
            float x0 = hv.x * LOG2E, x1 = hv.y * LOG2E;
            float x2 = hv.z * LOG2E, x3 = hv.w * LOG2E;
            hp[4 * q + 0] = f32x2{x0, x0};
            hp[4 * q + 1] = f32x2{x1, x1};
            hp[4 * q + 2] = f32x2{x2, x2};
            hp[4 * q + 3] = f32x2{x3, x3};
        }
    }

    const float* wbase = Wo + c0;
    float acc = 0.f, acc2 = 0.f;

    // 31 iterations x 16 cols (496)
    for (int v = 0; v < CSL - 4; v += 16) {
        f32x2 cp[8];
        #pragma unroll
        for (int p = 0; p < 8; ++p) cp[p] = f32x2{0.f, 0.f};
        #pragma unroll
        for (int k = 0; k < HID; ++k) {
            f32x16 w16 = *(const f32x16*)(wbase + (size_t)k * VOCAB + v);
            #pragma unroll
            for (int p = 0; p < 8; ++p) {
                f32x2 wp2 = f32x2{w16[2 * p], w16[2 * p + 1]};
                asm("v_pk_fma_f32 %0, %1, %2, %0"
                    : "+v"(cp[p]) : "v"(hp[k]), "s"(wp2));
            }
        }
        #pragma unroll
        for (int p = 0; p < 8; ++p) {
            acc  += __builtin_amdgcn_exp2f(cp[p].x);
            acc2 += __builtin_amdgcn_exp2f(cp[p].y);
        }
    }
    // 4-col tail (v = 496)
    {
        const int v = CSL - 4;
        f32x2 a01 = {0.f, 0.f}, a23 = {0.f, 0.f};
        #pragma unroll
        for (int k = 0; k < HID; ++k) {
            f32x4 w4 = *(const f32x4*)(wbase + (size_t)k * VOCAB + v);
            asm("v_pk_fma_f32 %0, %1, %2, %0"
                : "+v"(a01) : "v"(hp[k]), "s"(w4.xy));
            asm("v_pk_fma_f32 %0, %1, %2, %0"
                : "+v"(a23) : "v"(hp[k]), "s"(w4.zw));
        }
        acc  += __builtin_amdgcn_exp2f(a01.x) + __builtin_amdgcn_exp2f(a23.x);
        acc2 += __builtin_amdgcn_exp2f(a01.y) + __builtin_amdgcn_exp2f(a23.y);
    }

    part[wave][lane] = acc + acc2;
    __syncthreads();
    if (wave == 0) {
        float tot = part[0][lane] + part[1][lane]
                  + part[2][lane] + part[3][lane];
        P[(size_t)cchunk * NROW + row0 + lane] = tot;  // written exactly once
    }
}

// ---------------------------------------------------------------------------
// K3 (v4): output pass, RV 64->32 (grid 2048 = 4 blocks/CU, 32 waves/CU):
// R11 measured 4.85 TB/s at only 2 blocks/CU; fill hits 6.9 — test whether
// store-queue parallelism was the limiter. NT stores (R6/R15: mandatory).
// ---------------------------------------------------------------------------
#define RV 32     // rows per block
#define VSK 2048  // vocab cols per block slice

__global__ __launch_bounds__(512, 4) void write_logits(
    const float* __restrict__ H, const float* __restrict__ Wo,
    const float* __restrict__ P, float* __restrict__ out)
{
    __shared__ __align__(16) float sH[RV * HID];  // 2 KB
    __shared__ __align__(16) float sLogS[RV];

    const int tid = threadIdx.x;
    const int vtile = blockIdx.x & 15;
    const int row0 = (blockIdx.x >> 4) * RV;

    if (tid < RV * HID / 4)
        *(float4*)(sH + 4 * tid) = *(const float4*)(H + row0 * HID + 4 * tid);
    if (tid < RV) {  // fused logS: 16 partials per row
        float tot = 0.f;
        #pragma unroll
        for (int p = 0; p < 16; ++p) tot += P[(size_t)p * NROW + row0 + tid];
        sLogS[tid] = __logf(tot);
    }
    __syncthreads();

    const int v = vtile * VSK + 4 * tid;
    if (v >= VOCAB) return;  // tile-15 tail; no barriers below

    f32x2 wlo[HID], whi[HID];
    #pragma unroll
    for (int k = 0; k < HID; ++k) {
        f32x4 w4 = *(const f32x4*)(Wo + (size_t)k * VOCAB + v);
        wlo[k] = w4.xy; whi[k] = w4.zw;
    }
    const f32x4* sH4 = (const f32x4*)sH;
    const f32x4* sLS4 = (const f32x4*)sLogS;

    float* orow = out + (size_t)row0 * VOCAB + v;
    for (int r4 = 0; r4 < RV; r4 += 4) {
        f32x4 ls4 = sLS4[r4 >> 2];
        #pragma unroll
        for (int rr = 0; rr < 4; ++rr) {
            const int r = r4 + rr;
            f32x2 l01 = {0.f, 0.f}, l23 = {0.f, 0.f};
            #pragma unroll
            for (int q = 0; q < 4; ++q) {
                f32x4 hv = sH4[r * 4 + q];  // uniform addr b128 broadcast
                l01 += hv.x * wlo[4*q+0]; l23 += hv.x * whi[4*q+0];
                l01 += hv.y * wlo[4*q+1]; l23 += hv.y * whi[4*q+1];
                l01 += hv.z * wlo[4*q+2]; l23 += hv.z * whi[4*q+2];
                l01 += hv.w * wlo[4*q+3]; l23 += hv.w * whi[4*q+3];
            }
            const float ls = (rr == 0) ? ls4.x : (rr == 1) ? ls4.y
                           : (rr == 2) ? ls4.z : ls4.w;
            f32x4 o;
            o.xy = l01 - ls;
            o.zw = l23 - ls;
            __builtin_nontemporal_store(o, (f32x4*)orow);
            orow += VOCAB;
        }
    }
}

extern "C" void kernel_launch(void* const* d_in, const int* in_sizes, int n_in,
                              void* d_out, int out_size, void* d_ws, size_t ws_size,
                              hipStream_t stream) {
    const int*   idx    = (const int*)d_in[0];    // [SEQ, BATCH] int32
    const float* lookup = (const float*)d_in[1];  // [VOCAB, EMB]
    const float* Wx     = (const float*)d_in[2];  // [EMB, HID]
    const float* Wh     = (const float*)d_in[3];  // [HID, HID]
    const float* Wo     = (const float*)d_in[4];  // [HID, VOCAB]
    float* out = (float*)d_out;                   // [SEQ, BATCH, VOCAB]

    // ws layout: H (256 KB) | A (256 KB, dead after rnn) reused as P (256 KB)
    float* Hbuf = (float*)d_ws;
    float* A    = Hbuf + NROW * HID;
    float* P    = A;  // alias: A consumed by rnn_recur before sum writes P

    embed_xw<<<128, 512, 0, stream>>>(idx, lookup, Wx, A);
    rnn_recur<<<1, 512, 0, stream>>>(A, Wh, Hbuf);
    sum_exp_partial<<<64 * 16, 256, 0, stream>>>(Hbuf, Wo, P);
    write_logits<<<16 * (NROW / RV), 512, 0, stream>>>(Hbuf, Wo, P, out);
}